// Round 6
// baseline (314.367 us; speedup 1.0000x reference)
//
#include <hip/hip_runtime.h>

#define T      792
#define ND     99
#define NL     16
#define KBLK   25        // 25 k-blocks of 32 (K padded 792 -> 800)
#define BATCH  65536
#define NTILES (BATCH / 16)   // 4096 tiles of 16 batch rows

typedef __attribute__((ext_vector_type(8))) short  short8;   // 8 bf16 in 4 VGPRs
typedef __attribute__((ext_vector_type(4))) float  float4v;

// f32 -> bf16 round-to-nearest-even
__device__ inline unsigned short f2bf(float x) {
    union { float f; unsigned u; } c; c.f = x;
    return (unsigned short)((c.u + 0x7FFFu + ((c.u >> 16) & 1u)) >> 16);
}

__device__ __forceinline__ short8 pack_a(const float4v a0, const float4v a1, const float d) {
    union { unsigned short us[8]; short8 v; } af;
    af.us[0] = f2bf(a0.x * d); af.us[1] = f2bf(a0.y * d);
    af.us[2] = f2bf(a0.z * d); af.us[3] = f2bf(a0.w * d);
    af.us[4] = f2bf(a1.x * d); af.us[5] = f2bf(a1.y * d);
    af.us[6] = f2bf(a1.z * d); af.us[7] = f2bf(a1.w * d);
    return af.v;
}

// K-half over 2 tiles: B one-hot built ONCE per k-step, feeds two MFMAs.
// Depth-2 circular register prefetch per tile (~8-10 loads in flight).
template<int KB0, int NKB>
__device__ __forceinline__ void k_half(
    const float* __restrict__ arow0, const float* __restrict__ drow0,
    const float* __restrict__ arow1, const float* __restrict__ drow1,
    const unsigned* __restrict__ packed, const int g, const int n,
    float4v& acc0, float4v& acc1)
{
    constexpr int PF = 2;
    float4v A00[PF], A01[PF], A10[PF], A11[PF];
    float   D0[PF], D1[PF];
#pragma unroll
    for (int p = 0; p < PF; ++p) {
        const int idx = (KB0 + p) * 4 + g;
        const int kc  = min(idx * 8, T - 8);
        A00[p] = *(const float4v*)(arow0 + kc);
        A01[p] = *(const float4v*)(arow0 + kc + 4);
        A10[p] = *(const float4v*)(arow1 + kc);
        A11[p] = *(const float4v*)(arow1 + kc + 4);
        D0[p]  = (idx < ND) ? drow0[idx] : 0.f;   // only pad block (idx==99) zeroes
        D1[p]  = (idx < ND) ? drow1[idx] : 0.f;
    }
#pragma unroll
    for (int i = 0; i < NKB; ++i) {
        const int slot = i & (PF - 1);            // static after full unroll
        const int idx  = (KB0 + i) * 4 + g;
        const unsigned u = packed[idx];           // LDS broadcast within 16-lane group

        union { unsigned short us[8]; short8 v; } bf;
#pragma unroll
        for (int j = 0; j < 8; ++j)
            bf.us[j] = (((u >> (4 * j)) & 15u) == (unsigned)n)
                           ? (unsigned short)0x3F80 : (unsigned short)0;

        const short8 af0 = pack_a(A00[slot], A01[slot], D0[slot]);
        const short8 af1 = pack_a(A10[slot], A11[slot], D1[slot]);

        if (i + PF < NKB) {                       // refill freed slot
            const int idx2 = (KB0 + i + PF) * 4 + g;
            const int kc2  = min(idx2 * 8, T - 8);
            A00[slot] = *(const float4v*)(arow0 + kc2);
            A01[slot] = *(const float4v*)(arow0 + kc2 + 4);
            A10[slot] = *(const float4v*)(arow1 + kc2);
            A11[slot] = *(const float4v*)(arow1 + kc2 + 4);
            D0[slot]  = (idx2 < ND) ? drow0[idx2] : 0.f;
            D1[slot]  = (idx2 < ND) ? drow1[idx2] : 0.f;
        }

        acc0 = __builtin_amdgcn_mfma_f32_16x16x32_bf16(af0, bf.v, acc0, 0, 0, 0);
        acc1 = __builtin_amdgcn_mfma_f32_16x16x32_bf16(af1, bf.v, acc1, 0, 0, 0);
    }
}

// Loss of one 16-row tile from combined accumulator. Valid on lane 0 only.
__device__ __forceinline__ float tile_loss(const float4v c, const float invcap, const int n) {
    float lsum = 0.f;
#pragma unroll
    for (int r = 0; r < 4; ++r) {
        const float u = c[r] * invcap;
        float s = u, q = u * u, m = u;
#pragma unroll
        for (int off = 8; off >= 1; off >>= 1) {
            s += __shfl_xor(s, off, 16);
            q += __shfl_xor(q, off, 16);
            const float om = __shfl_xor(m, off, 16);
            m = m > om ? m : om;
        }
        if (n == 0) {
            const float var = (q - s * s * (1.0f / 16.0f)) * (1.0f / 15.0f);  // ddof=1
            lsum += var + 0.5f * m;
        }
    }
    lsum += __shfl_xor(lsum, 16, 64);   // fold the 4 group leaders
    lsum += __shfl_xor(lsum, 32, 64);
    return lsum;
}

__global__ __launch_bounds__(256) void llb_mfma(
    const float* __restrict__ pred,   // [BATCH, 792]
    const float* __restrict__ dem,    // [BATCH, 99]
    const int*   __restrict__ t2l,    // [792]
    const float* __restrict__ cap,    // [16]
    float* __restrict__ partial)      // [NTILES]
{
    __shared__ unsigned packed[KBLK * 4];   // word w = links of k=8w..8w+7 (4b each)
    __shared__ float4v  comb[2][2][64];     // [pair][tile][lane] odd-wave handoff

    const int lane = threadIdx.x & 63;
    const int wid  = threadIdx.x >> 6;
    const int g    = lane >> 4;             // k-group 0..3
    const int n    = lane & 15;             // col (link) / A-row-in-tile

    if (threadIdx.x < KBLK * 4) {
        const int w = threadIdx.x;
        unsigned u = 0;
#pragma unroll
        for (int j = 0; j < 8; ++j) {
            const int k = w * 8 + j;
            const unsigned link = (k < T) ? (unsigned)t2l[k] : 0u;  // pad unused (d=0)
            u |= link << (4 * j);
        }
        packed[w] = u;
    }
    __syncthreads();

    const int pair = wid >> 1;
    const int t0   = (int)blockIdx.x * 4 + pair * 2;  // 1024 blocks * 2 pairs * 2 tiles
    const int t1   = t0 + 1;
    const int r0   = t0 * 16 + n;                     // A fragment: m = lane&15
    const int r1   = t1 * 16 + n;
    const float* __restrict__ arow0 = pred + (size_t)r0 * T;
    const float* __restrict__ drow0 = dem  + (size_t)r0 * ND;
    const float* __restrict__ arow1 = pred + (size_t)r1 * T;
    const float* __restrict__ drow1 = dem  + (size_t)r1 * ND;

    float4v acc0 = {0.f, 0.f, 0.f, 0.f};
    float4v acc1 = {0.f, 0.f, 0.f, 0.f};
    if (wid & 1) k_half<13, 12>(arow0, drow0, arow1, drow1, packed, g, n, acc0, acc1);
    else         k_half<0, 13>(arow0, drow0, arow1, drow1, packed, g, n, acc0, acc1);

    // Combine K-split halves: odd wave hands its accs to its even partner.
    if (wid & 1) { comb[pair][0][lane] = acc0; comb[pair][1][lane] = acc1; }
    __syncthreads();
    if (!(wid & 1)) {
        const float invcap = 1.0f / (cap[n] + 1e-8f);
        const float4v o0 = comb[pair][0][lane];
        const float4v o1 = comb[pair][1][lane];
        // C/D layout (HW-verified): col = lane&15 (= link), row = (lane>>4)*4 + reg.
        const float4v c0 = {acc0[0] + o0[0], acc0[1] + o0[1], acc0[2] + o0[2], acc0[3] + o0[3]};
        const float4v c1 = {acc1[0] + o1[0], acc1[1] + o1[1], acc1[2] + o1[2], acc1[3] + o1[3]};
        const float l0 = tile_loss(c0, invcap, n);
        const float l1 = tile_loss(c1, invcap, n);
        if (lane == 0) { partial[t0] = l0; partial[t1] = l1; }
    }
}

__global__ __launch_bounds__(256) void llb_reduce(
    const float* __restrict__ partial, float* __restrict__ out)
{
    float s = 0.f;
    for (int i = threadIdx.x; i < NTILES; i += 256) s += partial[i];
#pragma unroll
    for (int off = 32; off >= 1; off >>= 1) s += __shfl_xor(s, off, 64);
    __shared__ float red[4];
    if ((threadIdx.x & 63) == 0) red[threadIdx.x >> 6] = s;
    __syncthreads();
    if (threadIdx.x == 0)
        out[0] = (red[0] + red[1] + red[2] + red[3]) * (1.0f / (float)BATCH);
}

extern "C" void kernel_launch(void* const* d_in, const int* in_sizes, int n_in,
                              void* d_out, int out_size, void* d_ws, size_t ws_size,
                              hipStream_t stream) {
    const float* pred = (const float*)d_in[0];
    const float* dem  = (const float*)d_in[1];
    const int*   t2l  = (const int*)d_in[2];
    const float* cap  = (const float*)d_in[3];
    float* out     = (float*)d_out;
    float* partial = (float*)d_ws;            // 4096 floats = 16 KB scratch

    llb_mfma<<<NTILES / 4, 256, 0, stream>>>(pred, dem, t2l, cap, partial);
    llb_reduce<<<1, 256, 0, stream>>>(partial, out);
}